// Round 1
// baseline (469.811 us; speedup 1.0000x reference)
//
#include <hip/hip_runtime.h>

#define NCOMP 8
#define NCONT 56
#define NCAT 8
#define NU 100
#define SEPC 1e-3f
#define T1F 10.0f

// One combined weight array: per feature f (0..55), 35 float4 "roles":
//  role 2c+t      : Wh comp c, k=8t..8t+7   (16 roles)
//  role 16+2c+t   : Wv comp c, k=8t..8t+7   (16 roles)
//  role 32+t      : Wic,       k=8t..8t+7   (2 roles)
//  role 34        : pad
#define FSTRIDE 35
#define WS_NW4 2048            // float4 count of packed weight image (padded)
#define WS_BIAS_OFF 32768      // byte offset of biases inside workspace

typedef __fp16 f16x2 __attribute__((ext_vector_type(2)));
typedef _Float16 h2arith __attribute__((ext_vector_type(2)));

union H8 { f16x2 h2[4]; float4 f4; };

__device__ __forceinline__ float sp(float x) {
    // softplus = ln2 * log2(1 + 2^(x*log2e)) via v_exp_f32/v_log_f32
    return 0.69314718f * __builtin_amdgcn_logf(1.0f + __builtin_amdgcn_exp2f(x * 1.44269504f));
}

__device__ __forceinline__ f16x2 pkrtz(float a, float b) {
    return __builtin_amdgcn_cvt_pkrtz(a, b);
}

__device__ __forceinline__ float fdot2(f16x2 a, f16x2 b, float c) {
    return __builtin_amdgcn_fdot2(a, b, c, false);
}

__device__ __forceinline__ h2arith h2shfl_xor(h2arith v, int off) {
    int i = __builtin_bit_cast(int, v);
    i = __shfl_xor(i, off, 64);
    return __builtin_bit_cast(h2arith, i);
}

// One continuous-feature accumulation against LDS weights.
// Weight reads are software-pipelined (double-buffered in registers) so the
// ds_read latency of comp c+1 hides under comp c's 16 fdot2 + 2 softplus.
__device__ __forceinline__ void acc_cont(const float4* __restrict__ pw,
                                         float4 a0, float4 a1, float4 a2, float4 a3,
                                         float* sh, float* sw, float& ic) {
    f16x2 ba[8];
    ba[0] = pkrtz(a0.x, a0.y); ba[1] = pkrtz(a0.z, a0.w);
    ba[2] = pkrtz(a1.x, a1.y); ba[3] = pkrtz(a1.z, a1.w);
    ba[4] = pkrtz(a2.x, a2.y); ba[5] = pkrtz(a2.z, a2.w);
    ba[6] = pkrtz(a3.x, a3.y); ba[7] = pkrtz(a3.z, a3.w);
    H8 u0, u1, v0, v1;
    u0.f4 = pw[0];  u1.f4 = pw[1];
    v0.f4 = pw[16]; v1.f4 = pw[17];
#pragma unroll
    for (int c = 0; c < NCOMP; ++c) {
        H8 nu0, nu1, nv0, nv1;
        if (c < NCOMP - 1) {
            nu0.f4 = pw[2 * c + 2];  nu1.f4 = pw[2 * c + 3];
            nv0.f4 = pw[18 + 2 * c]; nv1.f4 = pw[19 + 2 * c];
        } else {
            // prefetch the IC weights under the last comp's compute
            nu0.f4 = pw[32]; nu1.f4 = pw[33];
            nv0.f4 = u0.f4;  nv1.f4 = u1.f4;   // dead after loop
        }
        float hA = 0.0f, vA = 0.0f;
#pragma unroll
        for (int p = 0; p < 4; ++p) {
            hA = fdot2(ba[p], u0.h2[p], hA);
            vA = fdot2(ba[p], v0.h2[p], vA);
        }
#pragma unroll
        for (int p = 0; p < 4; ++p) {
            hA = fdot2(ba[4 + p], u1.h2[p], hA);
            vA = fdot2(ba[4 + p], v1.h2[p], vA);
        }
        sh[c] += sp(hA);
        sw[c] += sp(vA);
        u0 = nu0; u1 = nu1; v0 = nv0; v1 = nv1;
    }
    float iA = 0.0f;
#pragma unroll
    for (int p = 0; p < 4; ++p) iA = fdot2(ba[p], u0.h2[p], iA);
#pragma unroll
    for (int p = 0; p < 4; ++p) iA = fdot2(ba[4 + p], u1.h2[p], iA);
    ic += iA;   // IC has no softplus
}

// ---- prep: pack fp16 weights + softplus'd biases into workspace (once) ----
__global__ __launch_bounds__(512) void prep_kernel(
    const float* __restrict__ Wh, const float* __restrict__ Wv,
    const float* __restrict__ Wic, const float* __restrict__ bh,
    const float* __restrict__ bv, const float* __restrict__ bic,
    float4* __restrict__ ws)
{
    const int id = blockIdx.x * 512 + threadIdx.x;   // 0..2047 (grid=4)
    const int i  = id / FSTRIDE;
    const int rr = id - i * FSTRIDE;
    H8 u;
    u.f4 = make_float4(0.f, 0.f, 0.f, 0.f);
    if (i < NCONT && rr < 34) {
        if (rr < 32) {
            const int c = (rr & 15) >> 1;
            const int t = rr & 1;
            const float* W  = (rr < 16) ? Wh : Wv;
            const float* gp = W + (size_t)(8 * t) * 448 + i * 8 + c;
#pragma unroll
            for (int p = 0; p < 4; ++p)
                u.h2[p] = pkrtz(gp[(2 * p) * 448], gp[(2 * p + 1) * 448]);
        } else {
            const int t = rr - 32;
            const float* gp = Wic + (size_t)(8 * t) * 56 + i;
#pragma unroll
            for (int p = 0; p < 4; ++p)
                u.h2[p] = pkrtz(gp[(2 * p) * 56], gp[(2 * p + 1) * 56]);
        }
    }
    ws[id] = u.f4;
    if (id < NCOMP) {
        float2* b2 = (float2*)((char*)ws + WS_BIAS_OFF);
        b2[id] = make_float2(sp(bh[id]), sp(bv[id]));
    }
    if (id == NCOMP) {
        *((float*)((char*)ws + WS_BIAS_OFF + 64)) = bic[0];
    }
}

// cap 128 VGPR (2 blocks/CU); do NOT force 8 waves/EU (prev session: spill).
__global__ __launch_bounds__(512, 4) void tpm_kernel(
    const float* __restrict__ B, const float* __restrict__ Bcat,
    const float* __restrict__ Whc, const float* __restrict__ Wvc,
    const float* __restrict__ Wicc, const float4* __restrict__ ws,
    float* __restrict__ out)
{
    __shared__ float4 sW[WS_NW4];           // 32768 B, packed f16 weights
    __shared__ float2 sBias[NCOMP];         // (sp(bh), sp(bv))
    __shared__ float  sBic;
    __shared__ int    sCode[8][4][NCAT];    // [wave][local row][cat feature]

    const int tid  = threadIdx.x;
    const int lane = tid & 63;
    const int widx = tid >> 6;              // 0..7
    const int s = lane & 15;                // sublane: feature group
    const int g = lane >> 4;                // row group 0..3
    const int R0 = (((blockIdx.x << 3) + widx) << 2);  // 4 rows per wave
    const int r = R0 + g;
    const float* browp = B + (size_t)r * 896;
    const float4* pcat = (const float4*)(Bcat + (size_t)R0 * 800);

    // ---- issue long-latency streaming loads FIRST: scan batch A + pass0 B ----
    float4 qa0 = pcat[lane];
    float4 qa1 = pcat[64 + lane];
    float4 qa2 = pcat[128 + lane];
    float4 qa3 = pcat[192 + lane];
    float4 cb0, cb1, cb2, cb3;
    {
        const float4* p = (const float4*)(browp + s * 16);
        cb0 = p[0]; cb1 = p[1]; cb2 = p[2]; cb3 = p[3];
    }

    // ---- cheap staging: packed image (L2-hot) -> LDS, 4 float4/thread ----
#pragma unroll
    for (int k = 0; k < 4; ++k) sW[tid + k * 512] = ws[tid + k * 512];
    if (tid < NCOMP) sBias[tid] = ((const float2*)((const char*)ws + WS_BIAS_OFF))[tid];
    if (tid == NCOMP) sBic = *((const float*)((const char*)ws + WS_BIAS_OFF + 64));
    __syncthreads();

    // one-hot scan chunk: recover (feature, code) from a float4 of Bcat
    auto do_scan = [&](float4 q, int it) {
        int idx = it * 64 + lane;
        if (it < 12 || idx < 800) {
            int row = idx / 200;
            int pos = idx - row * 200;          // float4 within row
            float n = (float)(4 * pos);
            float sc = q.x * (n + 1.0f) + q.y * (n + 2.0f) + q.z * (n + 3.0f) + q.w * (n + 4.0f);
            if (sc > 0.5f) {
                int p = (int)sc - 1;            // element within row's 800
                int f = p / NU;
                sCode[widx][row][f] = p - f * NU;
            }
        }
    };

    // ---- accumulators: 17 channels x 1 row ----
    float sh[NCOMP], sw[NCOMP];
    float ic = 0.0f;
#pragma unroll
    for (int c = 0; c < NCOMP; ++c) { sh[c] = sw[c] = 0.0f; }

    // ---- issue scan batch B + pass1 B ----
    float4 qb0 = pcat[256 + lane];
    float4 qb1 = pcat[320 + lane];
    float4 qb2 = pcat[384 + lane];
    float4 qb3 = pcat[448 + lane];
    float4 qb4 = pcat[512 + lane];
    float4 nb0, nb1, nb2, nb3;
    {
        const float4* p = (const float4*)(browp + (s + 16) * 16);
        nb0 = p[0]; nb1 = p[1]; nb2 = p[2]; nb3 = p[3];
    }

    // consume batch A (arrived under staging/barrier), then pass 0
    do_scan(qa0, 0); do_scan(qa1, 1); do_scan(qa2, 2); do_scan(qa3, 3);
    acc_cont(sW + s * FSTRIDE, cb0, cb1, cb2, cb3, sh, sw, ic);

    // ---- issue scan batch C + pass2 B ----
    float4 qc0 = pcat[576 + lane];
    float4 qc1 = pcat[640 + lane];
    float4 qc2 = pcat[704 + lane];
    float4 qc3 = make_float4(0.f, 0.f, 0.f, 0.f);
    if (lane < 32) qc3 = pcat[768 + lane];   // idx < 800 guard
    float4 mb0, mb1, mb2, mb3;
    {
        const float4* p = (const float4*)(browp + (s + 32) * 16);
        mb0 = p[0]; mb1 = p[1]; mb2 = p[2]; mb3 = p[3];
    }

    do_scan(qb0, 4); do_scan(qb1, 5); do_scan(qb2, 6); do_scan(qb3, 7); do_scan(qb4, 8);
    acc_cont(sW + (s + 16) * FSTRIDE, nb0, nb1, nb2, nb3, sh, sw, ic);

    do_scan(qc0, 9); do_scan(qc1, 10); do_scan(qc2, 11); do_scan(qc3, 12);
    __threadfence_block();                   // sCode visible within wave

    // ---- categorical gather (cat lanes) + pass3 B loads (cont lanes),
    //      both issued so their latency hides under pass 2 ----
    float4 p3a, p3b, p3c, p3d;
    float p3ic = 0.0f;
    if (s >= 8) {
        int fi = s - 8;
        int cc = sCode[widx][g][fi];
        int gA = fi * NU + cc;
        const float4* qh = (const float4*)(Whc + gA * 8);
        const float4* qv = (const float4*)(Wvc + gA * 8);
        p3a = qh[0]; p3b = qh[1]; p3c = qv[0]; p3d = qv[1];
        p3ic = Wicc[gA];
    }
    float4 db0, db1, db2, db3;
    if (s < 8) {
        const float4* p = (const float4*)(browp + (s + 48) * 16);
        db0 = p[0]; db1 = p[1]; db2 = p[2]; db3 = p[3];
    }

    acc_cont(sW + (s + 32) * FSTRIDE, mb0, mb1, mb2, mb3, sh, sw, ic);

    // ---- pass 3: cont for s<8, cat for s>=8 ----
    if (s < 8) {
        acc_cont(sW + (s + 48) * FSTRIDE, db0, db1, db2, db3, sh, sw, ic);
    } else {
        sh[0] += sp(p3a.x); sh[1] += sp(p3a.y); sh[2] += sp(p3a.z); sh[3] += sp(p3a.w);
        sh[4] += sp(p3b.x); sh[5] += sp(p3b.y); sh[6] += sp(p3b.z); sh[7] += sp(p3b.w);
        sw[0] += sp(p3c.x); sw[1] += sp(p3c.y); sw[2] += sp(p3c.z); sw[3] += sp(p3c.w);
        sw[4] += sp(p3d.x); sw[5] += sp(p3d.y); sw[6] += sp(p3d.z); sw[7] += sp(p3d.w);
        ic += p3ic;
    }

    // ---- pack and 4-step butterfly within each 16-lane group ----
    h2arith hw[NCOMP];
#pragma unroll
    for (int c = 0; c < NCOMP; ++c)
        hw[c] = __builtin_bit_cast(h2arith, pkrtz(sh[c], sw[c]));
#pragma unroll
    for (int off = 8; off >= 1; off >>= 1) {
#pragma unroll
        for (int c = 0; c < NCOMP; ++c)
            hw[c] = hw[c] + h2shfl_xor(hw[c], off);
        ic += __shfl_xor(ic, off, 64);
    }

    // ---- sublanes 0..8 emit (t, x) for this group's row ----
    if (s < 9) {
        int m = (s == 8) ? 7 : s;
        float tj = SEPC * (float)s;
        float xj = ic + sBic;
#pragma unroll
        for (int c = 0; c < NCOMP; ++c) {
            float2 bb2 = sBias[c];
            if (c < m) tj += (float)hw[c][0] + bb2.x;
            if (c < s) {
                float vv = (float)hw[c][1] + bb2.y;
                xj += (c & 1) ? -vv : vv;
            }
        }
        if (s == 8) tj = fmaxf(tj, T1F);
        float2 o; o.x = tj; o.y = xj;
        ((float2*)out)[(size_t)r * 9 + s] = o;
    }
}

extern "C" void kernel_launch(void* const* d_in, const int* in_sizes, int n_in,
                              void* d_out, int out_size, void* d_ws, size_t ws_size,
                              hipStream_t stream) {
    (void)in_sizes; (void)n_in; (void)out_size; (void)ws_size;
    const float* B    = (const float*)d_in[0];
    const float* Bcat = (const float*)d_in[1];
    const float* Wh   = (const float*)d_in[2];
    const float* Whc  = (const float*)d_in[3];
    const float* bh   = (const float*)d_in[4];
    const float* Wv   = (const float*)d_in[5];
    const float* Wvc  = (const float*)d_in[6];
    const float* bv   = (const float*)d_in[7];
    const float* Wic  = (const float*)d_in[8];
    const float* Wicc = (const float*)d_in[9];
    const float* bic  = (const float*)d_in[10];
    float* out = (float*)d_out;
    float4* ws = (float4*)d_ws;   // needs 32836 B: 32 KB weight image + biases

    // pack weights once (tiny), then the streaming kernel
    hipLaunchKernelGGL(prep_kernel, dim3(4), dim3(512), 0, stream,
                       Wh, Wv, Wic, bh, bv, bic, ws);
    // 1024 blocks x 8 waves x 4 rows = 32768 rows; 2 blocks/CU (VGPR ~128)
    hipLaunchKernelGGL(tpm_kernel, dim3(1024), dim3(512), 0, stream,
                       B, Bcat, Whc, Wvc, Wicc, ws, out);
}

// Round 2
// 260.347 us; speedup vs baseline: 1.8046x; 1.8046x over previous
//
#include <hip/hip_runtime.h>

#define NCOMP 8
#define NCONT 56
#define NCAT 8
#define NU 100
#define SEPC 1e-3f
#define T1F 10.0f

// One combined weight array: per feature f (0..55), 35 float4 "roles":
//  role 2c+t      : Wh comp c, k=8t..8t+7   (16 roles)
//  role 16+2c+t   : Wv comp c, k=8t..8t+7   (16 roles)
//  role 32+t      : Wic,       k=8t..8t+7   (2 roles)
//  role 34        : pad
#define FSTRIDE 35
#define WS_NW4 2048            // float4 count of packed weight image (padded)
#define WS_BIAS_OFF 32768      // byte offset of biases inside workspace

typedef __fp16 f16x2 __attribute__((ext_vector_type(2)));
typedef _Float16 h2arith __attribute__((ext_vector_type(2)));

union H8 { f16x2 h2[4]; float4 f4; };

__device__ __forceinline__ float sp(float x) {
    // softplus = ln2 * log2(1 + 2^(x*log2e)) via v_exp_f32/v_log_f32
    return 0.69314718f * __builtin_amdgcn_logf(1.0f + __builtin_amdgcn_exp2f(x * 1.44269504f));
}

__device__ __forceinline__ f16x2 pkrtz(float a, float b) {
    return __builtin_amdgcn_cvt_pkrtz(a, b);
}

__device__ __forceinline__ float fdot2(f16x2 a, f16x2 b, float c) {
    return __builtin_amdgcn_fdot2(a, b, c, false);
}

__device__ __forceinline__ h2arith h2shfl_xor(h2arith v, int off) {
    int i = __builtin_bit_cast(int, v);
    i = __shfl_xor(i, off, 64);
    return __builtin_bit_cast(h2arith, i);
}

// One continuous-feature accumulation against LDS weights.
__device__ __forceinline__ void acc_cont(const float4* __restrict__ pw,
                                         float4 a0, float4 a1, float4 a2, float4 a3,
                                         float* sh, float* sw, float& ic) {
    f16x2 ba[8];
    ba[0] = pkrtz(a0.x, a0.y); ba[1] = pkrtz(a0.z, a0.w);
    ba[2] = pkrtz(a1.x, a1.y); ba[3] = pkrtz(a1.z, a1.w);
    ba[4] = pkrtz(a2.x, a2.y); ba[5] = pkrtz(a2.z, a2.w);
    ba[6] = pkrtz(a3.x, a3.y); ba[7] = pkrtz(a3.z, a3.w);
#pragma unroll
    for (int c = 0; c < NCOMP; ++c) {
        H8 u0, u1, v0, v1;
        u0.f4 = pw[2 * c];      u1.f4 = pw[2 * c + 1];
        v0.f4 = pw[16 + 2 * c]; v1.f4 = pw[17 + 2 * c];
        float hA = 0.0f, vA = 0.0f;
#pragma unroll
        for (int p = 0; p < 4; ++p) {
            hA = fdot2(ba[p], u0.h2[p], hA);
            vA = fdot2(ba[p], v0.h2[p], vA);
        }
#pragma unroll
        for (int p = 0; p < 4; ++p) {
            hA = fdot2(ba[4 + p], u1.h2[p], hA);
            vA = fdot2(ba[4 + p], v1.h2[p], vA);
        }
        sh[c] += sp(hA);
        sw[c] += sp(vA);
    }
    H8 i0, i1;
    i0.f4 = pw[32]; i1.f4 = pw[33];
    float iA = 0.0f;
#pragma unroll
    for (int p = 0; p < 4; ++p) iA = fdot2(ba[p], i0.h2[p], iA);
#pragma unroll
    for (int p = 0; p < 4; ++p) iA = fdot2(ba[4 + p], i1.h2[p], iA);
    ic += iA;   // IC has no softplus
}

// ---- prep: pack fp16 weights + softplus'd biases into workspace (once) ----
__global__ __launch_bounds__(512) void prep_kernel(
    const float* __restrict__ Wh, const float* __restrict__ Wv,
    const float* __restrict__ Wic, const float* __restrict__ bh,
    const float* __restrict__ bv, const float* __restrict__ bic,
    float4* __restrict__ ws)
{
    const int id = blockIdx.x * 512 + threadIdx.x;   // 0..2047 (grid=4)
    const int i  = id / FSTRIDE;
    const int rr = id - i * FSTRIDE;
    H8 u;
    u.f4 = make_float4(0.f, 0.f, 0.f, 0.f);
    if (i < NCONT && rr < 34) {
        if (rr < 32) {
            const int c = (rr & 15) >> 1;
            const int t = rr & 1;
            const float* W  = (rr < 16) ? Wh : Wv;
            const float* gp = W + (size_t)(8 * t) * 448 + i * 8 + c;
#pragma unroll
            for (int p = 0; p < 4; ++p)
                u.h2[p] = pkrtz(gp[(2 * p) * 448], gp[(2 * p + 1) * 448]);
        } else {
            const int t = rr - 32;
            const float* gp = Wic + (size_t)(8 * t) * 56 + i;
#pragma unroll
            for (int p = 0; p < 4; ++p)
                u.h2[p] = pkrtz(gp[(2 * p) * 56], gp[(2 * p + 1) * 56]);
        }
    }
    ws[id] = u.f4;
    if (id < NCOMP) {
        float2* b2 = (float2*)((char*)ws + WS_BIAS_OFF);
        b2[id] = make_float2(sp(bh[id]), sp(bv[id]));
    }
    if (id == NCOMP) {
        *((float*)((char*)ws + WS_BIAS_OFF + 64)) = bic[0];
    }
}

// cap 128 VGPR; do NOT force 8 waves/EU (prev session: (512,8) => scratch spill).
__global__ __launch_bounds__(512, 4) void tpm_kernel(
    const float* __restrict__ B, const float* __restrict__ Bcat,
    const float* __restrict__ Whc, const float* __restrict__ Wvc,
    const float* __restrict__ Wicc, const float4* __restrict__ ws,
    float* __restrict__ out)
{
    __shared__ float4 sW[WS_NW4];           // 32768 B, packed f16 weights
    __shared__ float2 sBias[NCOMP];         // (sp(bh), sp(bv))
    __shared__ float  sBic;
    __shared__ int    sCode[8][4][NCAT];    // [wave][local row][cat feature]

    const int tid  = threadIdx.x;
    const int lane = tid & 63;
    const int widx = tid >> 6;              // 0..7
    const int s = lane & 15;                // sublane: feature group
    const int g = lane >> 4;                // row group 0..3
    const int R0 = (((blockIdx.x << 3) + widx) << 2);  // 4 rows per wave
    const int r = R0 + g;
    const float* browp = B + (size_t)r * 896;

    // ---- issue pass-0 B prefetch FIRST: HBM latency hides under staging ----
    float4 cb0, cb1, cb2, cb3;
    {
        const float4* p = (const float4*)(browp + s * 16);
        cb0 = p[0]; cb1 = p[1]; cb2 = p[2]; cb3 = p[3];
    }

    // ---- cheap staging: packed image (L2-hot) -> LDS, 4 float4/thread ----
#pragma unroll
    for (int k = 0; k < 4; ++k) sW[tid + k * 512] = ws[tid + k * 512];
    if (tid < NCOMP) sBias[tid] = ((const float2*)((const char*)ws + WS_BIAS_OFF))[tid];
    if (tid == NCOMP) sBic = *((const float*)((const char*)ws + WS_BIAS_OFF + 64));
    __syncthreads();

    // ---- full-wave cooperative one-hot scan of 4 rows (800 float4) ----
    {
        const float4* pc = (const float4*)(Bcat + (size_t)R0 * 800);
#pragma unroll
        for (int it = 0; it < 13; ++it) {
            int idx = it * 64 + lane;           // 0..831
            if (it < 12 || idx < 800) {
                int row = idx / 200;
                int pos = idx - row * 200;      // float4 within row
                float4 q = pc[idx];
                float n = (float)(4 * pos);
                float sc = q.x * (n + 1.0f) + q.y * (n + 2.0f) + q.z * (n + 3.0f) + q.w * (n + 4.0f);
                if (sc > 0.5f) {
                    int p = (int)sc - 1;        // element within row's 800
                    int f = p / NU;
                    sCode[widx][row][f] = p - f * NU;
                }
            }
        }
    }
    __threadfence_block();

    // ---- prefetch the categorical gather NOW (used only in pass 3) ----
    float4 p3a, p3b, p3c, p3d;
    float p3ic = 0.0f;
    if (s >= 8) {
        int fi = s - 8;
        int cc = sCode[widx][g][fi];
        int gA = fi * NU + cc;
        const float4* qh = (const float4*)(Whc + gA * 8);
        const float4* qv = (const float4*)(Wvc + gA * 8);
        p3a = qh[0]; p3b = qh[1]; p3c = qv[0]; p3d = qv[1];
        p3ic = Wicc[gA];
    }

    // ---- accumulators: 17 channels x 1 row ----
    float sh[NCOMP], sw[NCOMP];
    float ic = 0.0f;
#pragma unroll
    for (int c = 0; c < NCOMP; ++c) { sh[c] = sw[c] = 0.0f; }

    // ---- passes 0..2 (all lanes continuous), pipelined 1-deep ----
#pragma unroll
    for (int j = 0; j < 3; ++j) {
        float4 nb0, nb1, nb2, nb3;
        if (j < 2) {
            const float4* p = (const float4*)(browp + (s + 16 * (j + 1)) * 16);
            nb0 = p[0]; nb1 = p[1]; nb2 = p[2]; nb3 = p[3];
        } else {
            // pass-3 B data; clamp f for cat lanes (s>=8) to stay in-bounds,
            // their copy is discarded.
            int f3 = (s < 8) ? (s + 48) : 48;
            const float4* p = (const float4*)(browp + f3 * 16);
            nb0 = p[0]; nb1 = p[1]; nb2 = p[2]; nb3 = p[3];
        }
        acc_cont(sW + (s + 16 * j) * FSTRIDE, cb0, cb1, cb2, cb3, sh, sw, ic);
        cb0 = nb0; cb1 = nb1; cb2 = nb2; cb3 = nb3;
    }

    // ---- pass 3: cont for s<8 (buffered), cat for s>=8 (prefetched) ----
    if (s < 8) {
        acc_cont(sW + (s + 48) * FSTRIDE, cb0, cb1, cb2, cb3, sh, sw, ic);
    } else {
        sh[0] += sp(p3a.x); sh[1] += sp(p3a.y); sh[2] += sp(p3a.z); sh[3] += sp(p3a.w);
        sh[4] += sp(p3b.x); sh[5] += sp(p3b.y); sh[6] += sp(p3b.z); sh[7] += sp(p3b.w);
        sw[0] += sp(p3c.x); sw[1] += sp(p3c.y); sw[2] += sp(p3c.z); sw[3] += sp(p3c.w);
        sw[4] += sp(p3d.x); sw[5] += sp(p3d.y); sw[6] += sp(p3d.z); sw[7] += sp(p3d.w);
        ic += p3ic;
    }

    // ---- pack and 4-step butterfly within each 16-lane group ----
    h2arith hw[NCOMP];
#pragma unroll
    for (int c = 0; c < NCOMP; ++c)
        hw[c] = __builtin_bit_cast(h2arith, pkrtz(sh[c], sw[c]));
#pragma unroll
    for (int off = 8; off >= 1; off >>= 1) {
#pragma unroll
        for (int c = 0; c < NCOMP; ++c)
            hw[c] = hw[c] + h2shfl_xor(hw[c], off);
        ic += __shfl_xor(ic, off, 64);
    }

    // ---- sublanes 0..8 emit (t, x) for this group's row ----
    if (s < 9) {
        int m = (s == 8) ? 7 : s;
        float tj = SEPC * (float)s;
        float xj = ic + sBic;
#pragma unroll
        for (int c = 0; c < NCOMP; ++c) {
            float2 bb2 = sBias[c];
            if (c < m) tj += (float)hw[c][0] + bb2.x;
            if (c < s) {
                float vv = (float)hw[c][1] + bb2.y;
                xj += (c & 1) ? -vv : vv;
            }
        }
        if (s == 8) tj = fmaxf(tj, T1F);
        float2 o; o.x = tj; o.y = xj;
        ((float2*)out)[(size_t)r * 9 + s] = o;
    }
}

extern "C" void kernel_launch(void* const* d_in, const int* in_sizes, int n_in,
                              void* d_out, int out_size, void* d_ws, size_t ws_size,
                              hipStream_t stream) {
    (void)in_sizes; (void)n_in; (void)out_size; (void)ws_size;
    const float* B    = (const float*)d_in[0];
    const float* Bcat = (const float*)d_in[1];
    const float* Wh   = (const float*)d_in[2];
    const float* Whc  = (const float*)d_in[3];
    const float* bh   = (const float*)d_in[4];
    const float* Wv   = (const float*)d_in[5];
    const float* Wvc  = (const float*)d_in[6];
    const float* bv   = (const float*)d_in[7];
    const float* Wic  = (const float*)d_in[8];
    const float* Wicc = (const float*)d_in[9];
    const float* bic  = (const float*)d_in[10];
    float* out = (float*)d_out;
    float4* ws = (float4*)d_ws;   // needs 32836 B: 32 KB weight image + biases

    // pack weights once (tiny), then the streaming kernel
    hipLaunchKernelGGL(prep_kernel, dim3(4), dim3(512), 0, stream,
                       Wh, Wv, Wic, bh, bv, bic, ws);
    // 1024 blocks x 8 waves x 4 rows = 32768 rows; ~4 blocks/CU by LDS (34KB)
    hipLaunchKernelGGL(tpm_kernel, dim3(1024), dim3(512), 0, stream,
                       B, Bcat, Whc, Wvc, Wicc, ws, out);
}